// Round 12
// baseline (54.611 us; speedup 1.0000x reference)
//
#include <hip/hip_runtime.h>

// B=16, C=4, H=512, W=512 ; rows=64 ; row length=262144 ; k=26214
// answer = sum(topk loss per row) / (64*26214)
//
// Threshold-based top-k sum: f(T) = sum_{l>T} l + (k - N(T))*T has f'(T)=k-N(T)=0
// at the true k-th value => second-order accurate in T error. T from a 1/16 sample.
//
// r6-r11: six k_pass structures all pin at 3.2-3.4 TB/s logical; no pipe saturated.
// Remaining invariant: ~half the 128 MB input is L3-resident across replays and
// L3-hit service appears to drag the blend. r12: non-temporal loads (no-allocate,
// evict-first -> pure HBM streaming path) + finer tiles (4096 blocks) for tail.

#define ROWS 64
#define ROW_N4 65536            // float4 per row
#define K_SEL 26214u
#define THREADS 256
#define BINS 2048               // linear bins over [0,8), width 1/256
#define NSUB 4
#define CHUNK4 1024             // float4 per k_pass block per stream (16 KB)

// fast BCE-with-logits: max(x,0) - x*y + log1p(exp(-|x|))
__device__ __forceinline__ float loss_fast(float x, float y) {
    float a = fabsf(x);
    float t = __builtin_amdgcn_exp2f(a * -1.44269504088896f);       // e^-a
    float sp = 0.69314718055995f * __builtin_amdgcn_logf(1.0f + t); // ln2*log2(1+t)
    return fmaxf(x, 0.0f) - x * y + sp;
}
__device__ __forceinline__ unsigned bin_of(float l) {
    unsigned b = (unsigned)(l * 256.0f);
    return b > (BINS - 1u) ? (BINS - 1u) : b;
}

typedef float f4v __attribute__((ext_vector_type(4)));
// non-temporal 16B load: global_load_dwordx4 with nt (no-allocate / evict-first)
__device__ __forceinline__ float4 nt_load(const float4* p) {
    f4v v = __builtin_nontemporal_load(reinterpret_cast<const f4v*>(p));
    return make_float4(v.x, v.y, v.z, v.w);
}

// ---------- Phase A: sampled per-row histogram (counts only, 1/16 of data) ----------
__global__ __launch_bounds__(THREADS)
void k_sample(const float4* __restrict__ lg, const float4* __restrict__ tg,
              unsigned* __restrict__ gcnt) {
    __shared__ unsigned h[BINS * NSUB];          // 32 KB
    int t = threadIdx.x;
    for (int i = t; i < BINS * NSUB; i += THREADS) h[i] = 0;
    __syncthreads();

    int row = blockIdx.x >> 2;
    int s = blockIdx.x & 3;
    int sub = t & (NSUB - 1);

    float4 xs[4], ys[4];
#pragma unroll
    for (int i = 0; i < 4; ++i) {
        int idx = row * ROW_N4 + (s * 4 + i) * 4096 + t;
        xs[i] = nt_load(&lg[idx]);
        ys[i] = nt_load(&tg[idx]);
    }
#pragma unroll
    for (int i = 0; i < 4; ++i) {
        atomicAdd(&h[bin_of(loss_fast(xs[i].x, ys[i].x)) * NSUB + sub], 1u);
        atomicAdd(&h[bin_of(loss_fast(xs[i].y, ys[i].y)) * NSUB + sub], 1u);
        atomicAdd(&h[bin_of(loss_fast(xs[i].z, ys[i].z)) * NSUB + sub], 1u);
        atomicAdd(&h[bin_of(loss_fast(xs[i].w, ys[i].w)) * NSUB + sub], 1u);
    }
    __syncthreads();
    unsigned* gc = gcnt + row * BINS;
    const uint4* h4 = (const uint4*)h;
    for (int i = t; i < BINS; i += THREADS) {
        uint4 v = h4[i];
        unsigned c = v.x + v.y + v.z + v.w;
        if (c) atomicAdd(&gc[i], c);
    }
}

// ---------- Select per-row threshold T (sample quantile: 26214/16 = 1638) ----------
__global__ __launch_bounds__(THREADS)
void k_sel(const unsigned* __restrict__ gcnt, float* __restrict__ Trow) {
    const unsigned target = 1638u;
    int row = blockIdx.x;
    int t = threadIdx.x;
    __shared__ unsigned h[BINS];
    __shared__ unsigned csum[THREADS];
    for (int i = t; i < BINS; i += THREADS) h[i] = gcnt[row * BINS + i];
    __syncthreads();

    unsigned s = 0;
#pragma unroll
    for (int j = 0; j < 8; ++j) s += h[t * 8 + j];
    csum[t] = s;
    __syncthreads();
    for (int off = 1; off < THREADS; off <<= 1) {
        unsigned add = (t + off < THREADS) ? csum[t + off] : 0;
        __syncthreads();
        csum[t] += add;
        __syncthreads();
    }
    unsigned suffIncl = csum[t];
    unsigned suffExcl = (t + 1 < THREADS) ? csum[t + 1] : 0;
    if (suffExcl < target && suffIncl >= target) {
        unsigned cum = suffExcl;
        for (int j = 7; j >= 0; --j) {
            unsigned c = h[t * 8 + j];
            if (cum + c >= target) {
                Trow[row] = ((float)(t * 8 + j) + 0.5f) * (1.0f / 256.0f);
                break;
            }
            cum += c;
        }
    }
}

// ---------- Full pass: non-temporal stream, compare+accumulate in registers ----------
__global__ __launch_bounds__(THREADS)
void k_pass(const float4* __restrict__ lg, const float4* __restrict__ tg,
            const float* __restrict__ Trow,
            double* __restrict__ rowsum, unsigned* __restrict__ rowcnt) {
    __shared__ float red_s[THREADS];
    __shared__ unsigned red_c[THREADS];
    int t = threadIdx.x;
    int row = blockIdx.x >> 6;          // 64 chunks per row
    int chunk = blockIdx.x & 63;
    int base = row * ROW_N4 + chunk * CHUNK4;
    float T = Trow[row];

    float lsum = 0.0f;
    unsigned lcnt = 0;
#pragma unroll
    for (int j = 0; j < 4; ++j) {
        int idx = base + j * THREADS + t;
        float4 x = nt_load(&lg[idx]);
        float4 y = nt_load(&tg[idx]);
        float l0 = loss_fast(x.x, y.x);
        float l1 = loss_fast(x.y, y.y);
        float l2 = loss_fast(x.z, y.z);
        float l3 = loss_fast(x.w, y.w);
        if (l0 > T) { lsum += l0; ++lcnt; }
        if (l1 > T) { lsum += l1; ++lcnt; }
        if (l2 > T) { lsum += l2; ++lcnt; }
        if (l3 > T) { lsum += l3; ++lcnt; }
    }
    red_s[t] = lsum;
    red_c[t] = lcnt;
    __syncthreads();
    for (int off = THREADS / 2; off > 0; off >>= 1) {
        if (t < off) { red_s[t] += red_s[t + off]; red_c[t] += red_c[t + off]; }
        __syncthreads();
    }
    if (t == 0) {
        atomicAdd(&rowsum[row], (double)red_s[0]);
        atomicAdd(&rowcnt[row], red_c[0]);
    }
}

// ---------- Finalize: rowtot = sum_above + (k - N)*T ; mean over rows ----------
__global__ __launch_bounds__(ROWS)
void k_finalize(const double* __restrict__ rowsum, const unsigned* __restrict__ rowcnt,
                const float* __restrict__ Trow, float* __restrict__ out) {
    __shared__ double tot[ROWS];
    int r = threadIdx.x;
    double T = (double)Trow[r];
    double corr = ((double)(int)K_SEL - (double)(int)rowcnt[r]) * T;
    tot[r] = rowsum[r] + corr;
    __syncthreads();
    if (r == 0) {
        double s = 0.0;
        for (int i = 0; i < ROWS; ++i) s += tot[i];
        out[0] = (float)(s / ((double)ROWS * (double)K_SEL));
    }
}

extern "C" void kernel_launch(void* const* d_in, const int* in_sizes, int n_in,
                              void* d_out, int out_size, void* d_ws, size_t ws_size,
                              hipStream_t stream) {
    const float4* lg = (const float4*)d_in[0];
    const float4* tg = (const float4*)d_in[1];
    float* out = (float*)d_out;
    (void)in_sizes; (void)n_in; (void)out_size; (void)ws_size;

    // workspace layout
    char* ws = (char*)d_ws;
    unsigned* gcnt   = (unsigned*)(ws);                  // 64*2048*4 = 524288
    float*    Trow   = (float*)   (ws + 524288);         // 256
    double*   rowsum = (double*)  (ws + 524544);         // 512 (8-aligned)
    unsigned* rowcnt = (unsigned*)(ws + 525056);         // 256
    size_t small_bytes = 525312;

    (void)hipMemsetAsync(d_ws, 0, small_bytes, stream);

    k_sample<<<ROWS * 4, THREADS, 0, stream>>>(lg, tg, gcnt);
    k_sel<<<ROWS, THREADS, 0, stream>>>(gcnt, Trow);
    k_pass<<<ROWS * 64, THREADS, 0, stream>>>(lg, tg, Trow, rowsum, rowcnt);
    k_finalize<<<1, ROWS, 0, stream>>>(rowsum, rowcnt, Trow, out);
}